// Round 1
// baseline (1003.841 us; speedup 1.0000x reference)
//
#include <hip/hip_runtime.h>

#define T_SEQ 2048
#define NH    16
#define D_NOPE 128
#define D_ROPE 64
#define D_V   128
#define RANK  512
#define D_QIN 1536
#define D_HID 7168
#define D_QK  576           // RANK + D_ROPE
#define QF_N  3072          // NH*(D_NOPE+D_ROPE)
#define ATT_SCALE 0.07216878364870322f   // (192)^-0.5

typedef float  f32x4  __attribute__((ext_vector_type(4)));
typedef __bf16 bf16x8 __attribute__((ext_vector_type(8)));

__device__ __forceinline__ unsigned short f2bf(float x){
  union{float f; unsigned u;} v; v.f = x;
  return (unsigned short)((v.u + 0x7fffu + ((v.u >> 16) & 1u)) >> 16);
}
__device__ __forceinline__ float bf2f(unsigned short b){
  union{unsigned u; float f;} v; v.u = ((unsigned)b) << 16; return v.f;
}
__device__ __forceinline__ bf16x8 ld_frag(const unsigned short* p){
  union{ uint4 u; bf16x8 v; } w; w.u = *(const uint4*)p; return w.v;
}

// ---------------- fp32 -> bf16 bulk convert ----------------
__global__ void cvt_bf16_kernel(const float* __restrict__ in, unsigned short* __restrict__ out, long n){
  long i = ((long)blockIdx.x * blockDim.x + threadIdx.x) * 4;
  if (i + 3 < n){
    float4 f = *(const float4*)(in + i);
    ushort4 o; o.x = f2bf(f.x); o.y = f2bf(f.y); o.z = f2bf(f.z); o.w = f2bf(f.w);
    *(ushort4*)(out + i) = o;
  }
}

// ---------------- k_cat = [bf16(k_c) | rope(k_pe)] : (T, 576) ----------------
__global__ void prep_kcat_kernel(const float* __restrict__ kc, const float* __restrict__ kpe,
                                 const int* __restrict__ pos, const float* __restrict__ cosc,
                                 const float* __restrict__ sinc, unsigned short* __restrict__ kcat){
  int t = blockIdx.x; int tid = threadIdx.x;
  for (int c = tid; c < RANK; c += 256)
    kcat[(long)t * D_QK + c] = f2bf(kc[(long)t * RANK + c]);
  if (tid < 32){
    int p = pos[t];
    float c = cosc[p * 32 + tid], s = sinc[p * 32 + tid];
    float x1 = kpe[(long)t * D_ROPE + tid];
    float x2 = kpe[(long)t * D_ROPE + 32 + tid];
    kcat[(long)t * D_QK + RANK + tid]      = f2bf(x1 * c - x2 * s);
    kcat[(long)t * D_QK + RANK + 32 + tid] = f2bf(x2 * c + x1 * s);
  }
}

// ---------------- Vt = bf16(k_c)^T : (512, T) ----------------
__global__ void transpose_vt_kernel(const float* __restrict__ kc, unsigned short* __restrict__ vt){
  __shared__ unsigned short tile[64][65];
  int bi = blockIdx.x, bj = blockIdx.y, tid = threadIdx.x;
  for (int c = tid; c < 4096; c += 256){
    int i = c >> 6, j = c & 63;
    tile[i][j] = f2bf(kc[(long)(bi * 64 + i) * RANK + bj * 64 + j]);
  }
  __syncthreads();
  for (int c = tid; c < 4096; c += 256){
    int j = c >> 6, i = c & 63;
    vt[(long)(bj * 64 + j) * T_SEQ + bi * 64 + i] = tile[i][j];
  }
}

// ---------------- wukt[h][r][d] = bf16(kvb[h*256+d][r]) ----------------
__global__ void prep_wukt_kernel(const float* __restrict__ kvb, unsigned short* __restrict__ wukt){
  __shared__ unsigned short tile[64][65];
  int h = blockIdx.x, db = blockIdx.y, rb = blockIdx.z, tid = threadIdx.x;
  for (int c = tid; c < 4096; c += 256){
    int i = c >> 6, j = c & 63;   // i: d within 64, j: r within 64
    tile[i][j] = f2bf(kvb[(long)(h * 256 + db * 64 + i) * RANK + rb * 64 + j]);
  }
  __syncthreads();
  for (int c = tid; c < 4096; c += 256){
    int j = c >> 6, i = c & 63;
    wukt[(long)h * RANK * D_NOPE + (long)(rb * 64 + j) * D_NOPE + db * 64 + i] = tile[i][j];
  }
}

// ---------------- rope on q_pe: qf(t, h*192+128..191) -> qcat[h][t][512..575] ----------------
__global__ void rope_q_kernel(const unsigned short* __restrict__ qf, const int* __restrict__ pos,
                              const float* __restrict__ cosc, const float* __restrict__ sinc,
                              unsigned short* __restrict__ qcat){
  int t = blockIdx.x; int tid = threadIdx.x;
  int p = pos[t];
  for (int w = tid; w < 512; w += 256){
    int h = w >> 5, i = w & 31;
    float c = cosc[p * 32 + i], s = sinc[p * 32 + i];
    float x1 = bf2f(qf[(long)t * QF_N + h * 192 + 128 + i]);
    float x2 = bf2f(qf[(long)t * QF_N + h * 192 + 128 + 32 + i]);
    long base = (long)h * T_SEQ * D_QK + (long)t * D_QK + RANK;
    qcat[base + i]      = f2bf(x1 * c - x2 * s);
    qcat[base + 32 + i] = f2bf(x2 * c + x1 * s);
  }
}

// ---------------- generic NT bf16 GEMM: C = A(MxK) * B(NxK)^T ----------------
template<int OUT_BF16>
__global__ __launch_bounds__(256, 2) void gemm_nt_kernel(
    const unsigned short* __restrict__ A, long lda, long sA,
    const unsigned short* __restrict__ B, long ldb, long sB,
    void* __restrict__ Cv, long ldc, long sC,
    int M, int N, int K)
{
  const int bz = blockIdx.z;
  A += (long)bz * sA;
  B += (long)bz * sB;
  const int m0 = blockIdx.x * 128;
  const int n0 = blockIdx.y * 128;
  const int tid = threadIdx.x;
  const int lane = tid & 63, wave = tid >> 6;
  const int quad = lane >> 4, l16 = lane & 15;
  const int wm = wave & 1, wn = wave >> 1;

  __shared__ __align__(16) unsigned short As[128 * 32];
  __shared__ __align__(16) unsigned short Bs[128 * 32];

  f32x4 acc[4][4];
  #pragma unroll
  for (int mt = 0; mt < 4; ++mt)
    #pragma unroll
    for (int nt = 0; nt < 4; ++nt)
      acc[mt][nt] = (f32x4){0.f, 0.f, 0.f, 0.f};

  for (int k0 = 0; k0 < K; k0 += 32){
    __syncthreads();
    #pragma unroll
    for (int i = 0; i < 2; ++i){
      int c = i * 256 + tid;
      int row = c >> 2, col = (c & 3) * 8;
      *(uint4*)(&As[row * 32 + col]) = *(const uint4*)(A + (long)(m0 + row) * lda + k0 + col);
      *(uint4*)(&Bs[row * 32 + col]) = *(const uint4*)(B + (long)(n0 + row) * ldb + k0 + col);
    }
    __syncthreads();
    bf16x8 af[4], bg[4];
    #pragma unroll
    for (int mt = 0; mt < 4; ++mt) af[mt] = ld_frag(&As[(wm * 64 + mt * 16 + l16) * 32 + quad * 8]);
    #pragma unroll
    for (int nt = 0; nt < 4; ++nt) bg[nt] = ld_frag(&Bs[(wn * 64 + nt * 16 + l16) * 32 + quad * 8]);
    #pragma unroll
    for (int mt = 0; mt < 4; ++mt)
      #pragma unroll
      for (int nt = 0; nt < 4; ++nt)
        acc[mt][nt] = __builtin_amdgcn_mfma_f32_16x16x32_bf16(af[mt], bg[nt], acc[mt][nt], 0, 0, 0);
  }

  if (OUT_BF16){
    unsigned short* C = (unsigned short*)Cv + (long)bz * sC;
    #pragma unroll
    for (int mt = 0; mt < 4; ++mt)
      #pragma unroll
      for (int nt = 0; nt < 4; ++nt)
        #pragma unroll
        for (int r = 0; r < 4; ++r)
          C[(long)(m0 + wm * 64 + mt * 16 + quad * 4 + r) * ldc + n0 + wn * 64 + nt * 16 + l16] =
              f2bf(acc[mt][nt][r]);
  } else {
    float* C = (float*)Cv + (long)bz * sC;
    #pragma unroll
    for (int mt = 0; mt < 4; ++mt)
      #pragma unroll
      for (int nt = 0; nt < 4; ++nt)
        #pragma unroll
        for (int r = 0; r < 4; ++r)
          C[(long)(m0 + wm * 64 + mt * 16 + quad * 4 + r) * ldc + n0 + wn * 64 + nt * 16 + l16] =
              acc[mt][nt][r];
  }
}

// ---------------- causal MQA flash attention ----------------
// Q: qcat [NH][T][576], K: kcat [T][576], V^T: vt [512][T], out: olat [NH][T][512]
__global__ __launch_bounds__(256, 2) void attn_kernel(
    const unsigned short* __restrict__ qcat,
    const unsigned short* __restrict__ kcat,
    const unsigned short* __restrict__ vt,
    unsigned short* __restrict__ olat)
{
  const int h = blockIdx.y;
  const int tile = (int)gridDim.x - 1 - (int)blockIdx.x;   // long blocks first
  const int t0 = tile * 32;
  const int tid = threadIdx.x;
  const int lane = tid & 63, wave = tid >> 6;
  const int quad = lane >> 4, l16 = lane & 15;
  const int rh = (wave & 1) * 16;     // S row half
  const int ch2 = wave >> 1;          // S col half index
  const int ch = ch2 * 16;

  __shared__ __align__(16) unsigned short Ks[32 * 584];   // padded: 2-way-only bank conflicts
  __shared__ __align__(16) unsigned short Ps[32 * 40];
  __shared__ float wmax[2][32], wsum[2][32];
  __shared__ float m_run[32], l_run[32], alpha_s[32], mnew_s[32];

  // Q fragments in registers (A-layout: m=l16, k=quad*8+j), 18 x 32-dim chunks
  bf16x8 qf[18];
  {
    const unsigned short* qrow = qcat + (long)h * T_SEQ * D_QK + (long)(t0 + rh + l16) * D_QK;
    #pragma unroll
    for (int kk = 0; kk < 18; ++kk) qf[kk] = ld_frag(qrow + kk * 32 + quad * 8);
  }

  f32x4 oacc[2][8];
  #pragma unroll
  for (int a = 0; a < 2; ++a)
    #pragma unroll
    for (int b = 0; b < 8; ++b) oacc[a][b] = (f32x4){0.f, 0.f, 0.f, 0.f};

  if (tid < 32){ m_run[tid] = -3e38f; l_run[tid] = 0.f; }

  const int niter = tile + 1;
  for (int it = 0; it < niter; ++it){
    const int s0 = it * 32;
    // stage K tile (32 keys x 576 dims), 16B chunks
    #pragma unroll
    for (int i = 0; i < 9; ++i){
      int c = i * 256 + tid;
      int row = c / 72, col = (c - row * 72) * 8;
      uint4 v = *(const uint4*)(kcat + (long)(s0 + row) * D_QK + col);
      *(uint4*)(&Ks[row * 584 + col]) = v;
    }
    __syncthreads();                                        // b1

    // S tile (16x16 per wave): rows rh.., cols ch..
    f32x4 sacc = (f32x4){0.f, 0.f, 0.f, 0.f};
    #pragma unroll
    for (int kk = 0; kk < 18; ++kk){
      bf16x8 b = ld_frag(&Ks[(ch + l16) * 584 + kk * 32 + quad * 8]);
      sacc = __builtin_amdgcn_mfma_f32_16x16x32_bf16(qf[kk], b, sacc, 0, 0, 0);
    }

    float sv[4], mr[4];
    const bool last = (it == niter - 1);
    #pragma unroll
    for (int r = 0; r < 4; ++r){
      float v = sacc[r] * ATT_SCALE;
      if (last && (s0 + ch + l16 > t0 + rh + quad * 4 + r)) v = -3e38f;  // causal
      sv[r] = v; mr[r] = v;
    }
    #pragma unroll
    for (int d = 1; d < 16; d <<= 1)
      #pragma unroll
      for (int r = 0; r < 4; ++r) mr[r] = fmaxf(mr[r], __shfl_xor(mr[r], d, 64));
    if (l16 == 0){
      #pragma unroll
      for (int r = 0; r < 4; ++r) wmax[ch2][rh + quad * 4 + r] = mr[r];
    }
    __syncthreads();                                        // b2
    if (tid < 32){
      float mo = m_run[tid];
      float mn = fmaxf(mo, fmaxf(wmax[0][tid], wmax[1][tid]));
      mnew_s[tid] = mn; alpha_s[tid] = __expf(mo - mn); m_run[tid] = mn;
    }
    __syncthreads();                                        // b3
    float ps[4];
    #pragma unroll
    for (int r = 0; r < 4; ++r){
      int row = rh + quad * 4 + r;
      float p = __expf(sv[r] - mnew_s[row]);
      Ps[row * 40 + ch + l16] = f2bf(p);
      ps[r] = p;
    }
    #pragma unroll
    for (int d = 1; d < 16; d <<= 1)
      #pragma unroll
      for (int r = 0; r < 4; ++r) ps[r] += __shfl_xor(ps[r], d, 64);
    if (l16 == 0){
      #pragma unroll
      for (int r = 0; r < 4; ++r) wsum[ch2][rh + quad * 4 + r] = ps[r];
    }
    __syncthreads();                                        // b4
    if (tid < 32) l_run[tid] = alpha_s[tid] * l_run[tid] + wsum[0][tid] + wsum[1][tid];

    // rescale O then accumulate P@V ; wave owns v-cols [wave*128, wave*128+128)
    #pragma unroll
    for (int rt = 0; rt < 2; ++rt){
      float al[4];
      #pragma unroll
      for (int r = 0; r < 4; ++r) al[r] = alpha_s[rt * 16 + quad * 4 + r];
      #pragma unroll
      for (int ct = 0; ct < 8; ++ct)
        #pragma unroll
        for (int r = 0; r < 4; ++r) oacc[rt][ct][r] *= al[r];
    }
    bf16x8 pa[2];
    #pragma unroll
    for (int rt = 0; rt < 2; ++rt) pa[rt] = ld_frag(&Ps[(rt * 16 + l16) * 40 + quad * 8]);
    #pragma unroll
    for (int ct = 0; ct < 8; ++ct){
      int v = wave * 128 + ct * 16 + l16;
      bf16x8 bv = ld_frag(vt + (long)v * T_SEQ + s0 + quad * 8);  // one 64B line per (v,tile)
      #pragma unroll
      for (int rt = 0; rt < 2; ++rt)
        oacc[rt][ct] = __builtin_amdgcn_mfma_f32_16x16x32_bf16(pa[rt], bv, oacc[rt][ct], 0, 0, 0);
    }
    __syncthreads();                                        // b5
  }

  #pragma unroll
  for (int rt = 0; rt < 2; ++rt)
    #pragma unroll
    for (int r = 0; r < 4; ++r){
      int row = rt * 16 + quad * 4 + r;
      float inv = 1.0f / l_run[row];
      #pragma unroll
      for (int ct = 0; ct < 8; ++ct){
        int col = wave * 128 + ct * 16 + l16;
        olat[(long)h * T_SEQ * RANK + (long)(t0 + row) * RANK + col] = f2bf(oacc[rt][ct][r] * inv);
      }
    }
}

// ---------------- host launcher ----------------
extern "C" void kernel_launch(void* const* d_in, const int* in_sizes, int n_in,
                              void* d_out, int out_size, void* d_ws, size_t ws_size,
                              hipStream_t stream){
  const float* q    = (const float*)d_in[0];
  const float* kc   = (const float*)d_in[1];
  const float* kpe  = (const float*)d_in[2];
  const int*   pos  = (const int*)d_in[3];
  const float* wq   = (const float*)d_in[4];
  const float* kvb  = (const float*)d_in[5];
  const float* wo   = (const float*)d_in[6];
  const float* cosc = (const float*)d_in[7];
  const float* sinc = (const float*)d_in[8];
  float* out = (float*)d_out;

  char* ws = (char*)d_ws;
  size_t off = 0;
  auto alloc_us = [&](long nelem) -> unsigned short* {
    unsigned short* p = (unsigned short*)(ws + off);
    off += ((size_t)nelem * 2 + 255) & ~(size_t)255;
    return p;
  };
  unsigned short* q_bf   = alloc_us((long)T_SEQ * D_QIN);          // 2048x1536
  unsigned short* wq_bf  = alloc_us((long)QF_N * D_QIN);           // 3072x1536
  unsigned short* kvb_bf = alloc_us((long)NH * 256 * RANK);        // 4096x512
  unsigned short* wukt   = alloc_us((long)NH * RANK * D_NOPE);     // 16x512x128
  unsigned short* wo_bf  = alloc_us((long)D_HID * NH * D_V);       // 7168x2048
  unsigned short* kcat   = alloc_us((long)T_SEQ * D_QK);           // 2048x576
  unsigned short* vt     = alloc_us((long)RANK * T_SEQ);           // 512x2048
  unsigned short* qf_bf  = alloc_us((long)T_SEQ * QF_N);           // 2048x3072
  unsigned short* qcat   = alloc_us((long)NH * T_SEQ * D_QK);      // 16x2048x576
  unsigned short* olat   = alloc_us((long)NH * T_SEQ * RANK);      // 16x2048x512
  unsigned short* o_mid  = alloc_us((long)T_SEQ * NH * D_V);       // 2048x2048

  // conversions
  {
    long n;
    n = (long)T_SEQ * D_QIN;
    cvt_bf16_kernel<<<dim3((unsigned)(n / 1024)), 256, 0, stream>>>(q, q_bf, n);
    n = (long)QF_N * D_QIN;
    cvt_bf16_kernel<<<dim3((unsigned)(n / 1024)), 256, 0, stream>>>(wq, wq_bf, n);
    n = (long)NH * 256 * RANK;
    cvt_bf16_kernel<<<dim3((unsigned)(n / 1024)), 256, 0, stream>>>(kvb, kvb_bf, n);
    n = (long)D_HID * NH * D_V;
    cvt_bf16_kernel<<<dim3((unsigned)(n / 1024)), 256, 0, stream>>>(wo, wo_bf, n);
  }
  prep_kcat_kernel<<<dim3(T_SEQ), 256, 0, stream>>>(kc, kpe, pos, cosc, sinc, kcat);
  transpose_vt_kernel<<<dim3(T_SEQ / 64, RANK / 64), 256, 0, stream>>>(kc, vt);
  prep_wukt_kernel<<<dim3(NH, D_NOPE / 64, RANK / 64), 256, 0, stream>>>(kvb, wukt);

  // G1: qf = q @ wq^T  (2048 x 3072, K=1536), bf16 out
  gemm_nt_kernel<1><<<dim3(T_SEQ / 128, QF_N / 128), 256, 0, stream>>>(
      q_bf, D_QIN, 0, wq_bf, D_QIN, 0, (void*)qf_bf, QF_N, 0, T_SEQ, QF_N, D_QIN);

  rope_q_kernel<<<dim3(T_SEQ), 256, 0, stream>>>(qf_bf, pos, cosc, sinc, qcat);

  // G2 (batched over heads): qcat[h][:, 0:512] = q_nope_h @ wukt_h^T  (2048x512, K=128)
  gemm_nt_kernel<1><<<dim3(T_SEQ / 128, RANK / 128, NH), 256, 0, stream>>>(
      qf_bf, QF_N, 192,
      wukt, D_NOPE, (long)RANK * D_NOPE,
      (void*)qcat, D_QK, (long)T_SEQ * D_QK,
      T_SEQ, RANK, D_NOPE);

  // attention
  attn_kernel<<<dim3(T_SEQ / 32, NH), 256, 0, stream>>>(qcat, kcat, vt, olat);

  // G3 (batched): o_mid[:, h*128:(h+1)*128] = olat_h @ w_uv_h^T  (2048x128, K=512)
  gemm_nt_kernel<1><<<dim3(T_SEQ / 128, D_V / 128, NH), 256, 0, stream>>>(
      olat, RANK, (long)T_SEQ * RANK,
      kvb_bf + (long)128 * RANK, RANK, (long)256 * RANK,
      (void*)o_mid, (long)NH * D_V, (long)D_V,
      T_SEQ, D_V, RANK);

  // G4: out = o_mid @ wo^T  (2048 x 7168, K=2048), fp32 out
  gemm_nt_kernel<0><<<dim3(T_SEQ / 128, D_HID / 128), 256, 0, stream>>>(
      o_mid, (long)NH * D_V, 0, wo_bf, (long)NH * D_V, 0, (void*)out, D_HID, 0,
      T_SEQ, D_HID, (long)NH * D_V);
}